// Round 2
// baseline (5890.359 us; speedup 1.0000x reference)
//
#include <hip/hip_runtime.h>

// Problem constants (match reference setup_inputs)
#define N_VOX   120000
#define NUP_VOX 240000
constexpr float BN_EPS = 1e-5f;

__device__ __forceinline__ float lrelu(float x) { return x >= 0.f ? x : 0.01f * x; }

// ---------------------------------------------------------------------------
// Sparse conv: out[ok[m], co] += sum_ci feats[ik[m], ci] * W[k, ci, co]
// One block handles one k (blockIdx.y) and a grid-stride range of m.
// lane = output channel co. W column for this k lives in registers
// (wreg[ci] = W[k][ci][lane]). Map index m is wave-uniform; readfirstlane
// forces the row index into an SGPR so the feature-row loads become
// scalar/broadcast loads feeding v_fmac.
// ROWS = map entries processed per wave iteration (ILP).
// ---------------------------------------------------------------------------
template <int CIN, int ROWS>
__global__ __launch_bounds__(256) void sconv_kernel(
    const float* __restrict__ feats, const float* __restrict__ W,
    const int* __restrict__ idx_in, const int* __restrict__ idx_out,
    float* __restrict__ out, int M)
{
    const int lane = threadIdx.x & 63;
    const int wv   = threadIdx.x >> 6;   // wave id within block (0..3)
    const int k    = blockIdx.y;

    float wreg[CIN];
    const float* Wk = W + (size_t)k * CIN * 64;
#pragma unroll
    for (int ci = 0; ci < CIN; ++ci) wreg[ci] = Wk[ci * 64 + lane];

    const int* ikp = idx_in  + (size_t)k * M;
    const int* okp = idx_out + (size_t)k * M;

    const int stride = gridDim.x * 4 * ROWS;
    for (int m0 = (blockIdx.x * 4 + wv) * ROWS; m0 < M; m0 += stride) {
#pragma unroll
        for (int r = 0; r < ROWS; ++r) {
            int m = m0 + r;
            if (ROWS > 1 && m >= M) break;
            int ik = __builtin_amdgcn_readfirstlane(ikp[m]);
            int ok = __builtin_amdgcn_readfirstlane(okp[m]);
            const float* __restrict__ row = feats + (size_t)ik * CIN;
            float a0 = 0.f, a1 = 0.f, a2 = 0.f, a3 = 0.f;
#pragma unroll
            for (int ci = 0; ci < CIN; ci += 4) {
                a0 = fmaf(row[ci + 0], wreg[ci + 0], a0);
                a1 = fmaf(row[ci + 1], wreg[ci + 1], a1);
                a2 = fmaf(row[ci + 2], wreg[ci + 2], a2);
                a3 = fmaf(row[ci + 3], wreg[ci + 3], a3);
            }
            atomicAdd(out + (size_t)ok * 64 + lane, (a0 + a1) + (a2 + a3));
        }
    }
}

// ---------------------------------------------------------------------------
// Per-channel sum & sumsq of lrelu(x) over R rows (64 channels).
// st[0..63] = sum, st[64..127] = sumsq. st must be zeroed beforehand.
// ---------------------------------------------------------------------------
__global__ __launch_bounds__(256) void stats_kernel(
    const float* __restrict__ x, int R, float* __restrict__ st)
{
    const int lane = threadIdx.x & 63;
    const int wv   = threadIdx.x >> 6;
    float s = 0.f, q = 0.f;
    const int stride = gridDim.x * 4;
    for (int r = blockIdx.x * 4 + wv; r < R; r += stride) {
        float v = lrelu(x[(size_t)r * 64 + lane]);
        s += v;
        q = fmaf(v, v, q);
    }
    __shared__ float ls[4][64];
    __shared__ float lq[4][64];
    ls[wv][lane] = s;
    lq[wv][lane] = q;
    __syncthreads();
    if (wv == 0) {
        float S = ls[0][lane] + ls[1][lane] + ls[2][lane] + ls[3][lane];
        float Q = lq[0][lane] + lq[1][lane] + lq[2][lane] + lq[3][lane];
        atomicAdd(&st[lane], S);
        atomicAdd(&st[64 + lane], Q);
    }
}

// ---------------------------------------------------------------------------
// y = (lrelu(x) - mean) * rsqrt(var + eps) * g + b   (channel-wise), float4.
// ---------------------------------------------------------------------------
__global__ __launch_bounds__(256) void bn_apply_kernel(
    const float* __restrict__ x, float* __restrict__ y,
    const float* __restrict__ st, const float* __restrict__ g,
    const float* __restrict__ b, int R)
{
    __shared__ float sc[64];
    __shared__ float sh[64];
    const float invR = 1.f / (float)R;
    if (threadIdx.x < 64) {
        int ch = threadIdx.x;
        float m = st[ch] * invR;
        float v = st[64 + ch] * invR - m * m;
        float s = rsqrtf(v + BN_EPS) * g[ch];
        sc[ch] = s;
        sh[ch] = fmaf(-m, s, b[ch]);
    }
    __syncthreads();

    const size_t total = (size_t)R * 16;  // float4 count (64 ch / 4)
    size_t i = (size_t)blockIdx.x * blockDim.x + threadIdx.x;
    const size_t stride = (size_t)gridDim.x * blockDim.x;
    const float4* xv = (const float4*)x;
    float4* yv = (float4*)y;
    for (; i < total; i += stride) {
        int ch = (int)((i * 4) & 63);
        float4 v = xv[i];
        float4 o;
        o.x = fmaf(lrelu(v.x), sc[ch + 0], sh[ch + 0]);
        o.y = fmaf(lrelu(v.y), sc[ch + 1], sh[ch + 1]);
        o.z = fmaf(lrelu(v.z), sc[ch + 2], sh[ch + 2]);
        o.w = fmaf(lrelu(v.w), sc[ch + 3], sh[ch + 3]);
        yv[i] = o;
    }
}

extern "C" void kernel_launch(void* const* d_in, const int* in_sizes, int n_in,
                              void* d_out, int out_size, void* d_ws, size_t ws_size,
                              hipStream_t stream)
{
    const float* x_F   = (const float*)d_in[0];
    const float* skipF = (const float*)d_in[1];
    const float* Wt    = (const float*)d_in[2];
    const float* Wu    = (const float*)d_in[3];
    const float* W1    = (const float*)d_in[4];
    const float* W2    = (const float*)d_in[5];
    const float* W3    = (const float*)d_in[6];
    const float* g0 = (const float*)d_in[7];
    const float* b0 = (const float*)d_in[8];
    const float* g1 = (const float*)d_in[9];
    const float* b1 = (const float*)d_in[10];
    const float* g2 = (const float*)d_in[11];
    const float* b2 = (const float*)d_in[12];
    const float* g3 = (const float*)d_in[13];
    const float* b3 = (const float*)d_in[14];
    const int* mt_in  = (const int*)d_in[15];
    const int* mt_out = (const int*)d_in[16];
    const int* mu_in  = (const int*)d_in[17];
    const int* mu_out = (const int*)d_in[18];
    const int* m1_in  = (const int*)d_in[19];
    const int* m1_out = (const int*)d_in[20];
    const int* m2_in  = (const int*)d_in[21];
    const int* m2_out = (const int*)d_in[22];
    const int* m3_in  = (const int*)d_in[23];
    const int* m3_out = (const int*)d_in[24];

    // Workspace layout (f32): s0 [N,64], s1 [NUP,64], st [128].
    // d_out doubles as the second NUP x 64 scratch buffer (s2).
    float* s0 = (float*)d_ws;
    float* s1 = s0 + (size_t)N_VOX * 64;
    float* st = s1 + (size_t)NUP_VOX * 64;
    float* s2 = (float*)d_out;

    const dim3 blk(256);
    const int CB = 512;  // conv grid.x

    // ---- Stage 0: trans_dilao conv (Cin=128) -> lrelu -> BN, in s0 ----
    hipMemsetAsync(s0, 0, (size_t)N_VOX * 64 * sizeof(float), stream);
    hipMemsetAsync(st, 0, 128 * sizeof(float), stream);
    sconv_kernel<128, 1><<<dim3(CB, 27), blk, 0, stream>>>(x_F, Wt, mt_in, mt_out, s0, N_VOX);
    stats_kernel<<<dim3(768), blk, 0, stream>>>(s0, N_VOX, st);
    bn_apply_kernel<<<dim3(1024), blk, 0, stream>>>(s0, s0, st, g0, b0, N_VOX);

    // ---- Stage 1: transposed upsample conv + skip, in s1 ----
    hipMemcpyAsync(s1, skipF, (size_t)NUP_VOX * 64 * sizeof(float),
                   hipMemcpyDeviceToDevice, stream);
    sconv_kernel<64, 2><<<dim3(CB, 27), blk, 0, stream>>>(s0, Wu, mu_in, mu_out, s1, NUP_VOX);

    // ---- Stage 2: conv1 (K=9) -> lrelu -> BN, in d_out ----
    hipMemsetAsync(s2, 0, (size_t)NUP_VOX * 64 * sizeof(float), stream);
    hipMemsetAsync(st, 0, 128 * sizeof(float), stream);
    sconv_kernel<64, 2><<<dim3(CB, 9), blk, 0, stream>>>(s1, W1, m1_in, m1_out, s2, NUP_VOX);
    stats_kernel<<<dim3(768), blk, 0, stream>>>(s2, NUP_VOX, st);
    bn_apply_kernel<<<dim3(2048), blk, 0, stream>>>(s2, s2, st, g1, b1, NUP_VOX);

    // ---- Stage 3: conv2 (K=9) -> lrelu -> BN, in s1 ----
    hipMemsetAsync(s1, 0, (size_t)NUP_VOX * 64 * sizeof(float), stream);
    hipMemsetAsync(st, 0, 128 * sizeof(float), stream);
    sconv_kernel<64, 2><<<dim3(CB, 9), blk, 0, stream>>>(s2, W2, m2_in, m2_out, s1, NUP_VOX);
    stats_kernel<<<dim3(768), blk, 0, stream>>>(s1, NUP_VOX, st);
    bn_apply_kernel<<<dim3(2048), blk, 0, stream>>>(s1, s1, st, g2, b2, NUP_VOX);

    // ---- Stage 4: conv3 (K=27) -> lrelu -> BN -> d_out ----
    hipMemsetAsync(s2, 0, (size_t)NUP_VOX * 64 * sizeof(float), stream);
    hipMemsetAsync(st, 0, 128 * sizeof(float), stream);
    sconv_kernel<64, 2><<<dim3(CB, 27), blk, 0, stream>>>(s1, W3, m3_in, m3_out, s2, NUP_VOX);
    stats_kernel<<<dim3(768), blk, 0, stream>>>(s2, NUP_VOX, st);
    bn_apply_kernel<<<dim3(2048), blk, 0, stream>>>(s2, s2, st, g3, b3, NUP_VOX);
}